// Round 2
// baseline (3291.308 us; speedup 1.0000x reference)
//
#include <hip/hip_runtime.h>
#include <hip/hip_bf16.h>

#define S 2048
#define H 1024
#define NH 16
#define DH 64
#define RV 32
#define QT 4

typedef __hip_bfloat16 bf16;

__device__ __forceinline__ float b2f(bf16 v) { return __bfloat162float(v); }

// Flexible load: f==1 -> buffer holds fp32, f==0 -> buffer holds bf16.
__device__ __forceinline__ float ldf(const void* p, int i, int f) {
    return f ? ((const float*)p)[i] : b2f(((const bf16*)p)[i]);
}

// ---------------- dtype sniffer -------------------------------------------
// Reads first 256 uint32 words of x (<= half the buffer in either dtype).
// bf16 tensor: low 16 bits of each word = a sane bf16 value (exp <= ~130).
// fp32 tensor: low 16 bits = random mantissa bits (exp uniform 0..255).
__global__ void detect_dtype(const unsigned int* __restrict__ xw,
                             int* __restrict__ flag)
{
    __shared__ int cnt;
    if (threadIdx.x == 0) cnt = 0;
    __syncthreads();
    unsigned int w = xw[threadIdx.x];
    unsigned int ex = ((w & 0xffffu) >> 7) & 0xffu;
    int big = (ex > 134u) ? 1 : 0;
    #pragma unroll
    for (int off = 32; off > 0; off >>= 1) big += __shfl_xor(big, off, 64);
    if ((threadIdx.x & 63) == 0) atomicAdd(&cnt, big);
    __syncthreads();
    if (threadIdx.x == 0) *flag = (cnt > 60) ? 1 : 0;
}

// ---------------- QKV GEMM: C(fp32) = x @ W + b ----------------------------
// 64x64 block tile, BK=16, 256 threads, 4x4 per thread. grid.z selects Q/K/V.
__global__ __launch_bounds__(256) void qkv_gemm(
    const void* __restrict__ x,
    const void* __restrict__ Wq, const void* __restrict__ bq,
    const void* __restrict__ Wk, const void* __restrict__ bk,
    const void* __restrict__ Wv, const void* __restrict__ bv,
    float* __restrict__ Qo, float* __restrict__ Ko, float* __restrict__ Vo,
    const int* __restrict__ flag)
{
    const void* W; const void* bias; float* out;
    if (blockIdx.z == 0)      { W = Wq; bias = bq; out = Qo; }
    else if (blockIdx.z == 1) { W = Wk; bias = bk; out = Ko; }
    else                      { W = Wv; bias = bv; out = Vo; }
    const int f = *flag;

    __shared__ float As[16][65];   // [k][m]
    __shared__ float Bs[16][65];   // [k][n]
    const int tid = threadIdx.x;
    const int tx = tid & 15, ty = tid >> 4;
    const int rowb = blockIdx.y * 64;
    const int colb = blockIdx.x * 64;

    float acc[4][4] = {};
    for (int kb = 0; kb < H; kb += 16) {
        #pragma unroll
        for (int i = tid; i < 1024; i += 256) {
            int m = i >> 4, kk = i & 15;
            As[kk][m] = ldf(x, (rowb + m) * H + kb + kk, f);
        }
        #pragma unroll
        for (int i = tid; i < 1024; i += 256) {
            int n = i & 63, kk = i >> 6;
            Bs[kk][n] = ldf(W, (kb + kk) * H + colb + n, f);
        }
        __syncthreads();
        #pragma unroll
        for (int kk = 0; kk < 16; ++kk) {
            float a[4], b[4];
            #pragma unroll
            for (int i = 0; i < 4; ++i) a[i] = As[kk][ty * 4 + i];
            #pragma unroll
            for (int j = 0; j < 4; ++j) b[j] = Bs[kk][tx * 4 + j];
            #pragma unroll
            for (int i = 0; i < 4; ++i)
                #pragma unroll
                for (int j = 0; j < 4; ++j)
                    acc[i][j] += a[i] * b[j];
        }
        __syncthreads();
    }
    #pragma unroll
    for (int i = 0; i < 4; ++i) {
        int m = rowb + ty * 4 + i;
        #pragma unroll
        for (int j = 0; j < 4; ++j) {
            int n = colb + tx * 4 + j;
            out[m * H + n] = acc[i][j] + ldf(bias, n, f);
        }
    }
}

// ---------------- all_rel[q][h][r] = Q[q,h,:] . rel_emb[r,h,:] + rel_bias[r,h]
__global__ __launch_bounds__(256) void rel_scores_kernel(
    const float* __restrict__ Q, const void* __restrict__ rel_emb,
    const void* __restrict__ rel_bias, float* __restrict__ Rel,
    const int* __restrict__ flag)
{
    const int q = blockIdx.x;
    const int f = *flag;
    __shared__ float Qs[H];
    for (int i = threadIdx.x; i < H; i += 256) Qs[i] = Q[q * H + i];
    __syncthreads();
    for (int p = threadIdx.x; p < NH * RV; p += 256) {
        int h = p >> 5;      // p = h*32 + r
        int r = p & 31;
        const float* qs = Qs + h * DH;
        float acc = 0.f;
        #pragma unroll
        for (int d = 0; d < DH; ++d) acc += qs[d] * ldf(rel_emb, (r * NH + h) * DH + d, f);
        Rel[(q * NH + h) * RV + r] = acc + ldf(rel_bias, r * NH + h, f);
    }
}

// ---------------- attention: block = (4 queries) x (1 head) ----------------
__global__ __launch_bounds__(256) void attn_kernel(
    const float* __restrict__ Q, const float* __restrict__ Km,
    const float* __restrict__ Vm, const float* __restrict__ Rel,
    const int* __restrict__ att_mask, const int* __restrict__ rel_ids,
    float* __restrict__ ctx)
{
    const int h = blockIdx.y;
    const int q0 = blockIdx.x * QT;
    const int tid = threadIdx.x;

    __shared__ float Qs[QT][DH];
    __shared__ float Rl[QT][RV];
    __shared__ float Sc[QT][S];

    {   // load Q rows (fp32 from ws) and rel rows
        int qi = tid >> 6, d = tid & 63;               // 256 == QT*DH
        Qs[qi][d] = Q[(q0 + qi) * H + h * DH + d];
        if (tid < QT * RV) {
            int qr = tid >> 5, r = tid & 31;
            Rl[qr][r] = Rel[((q0 + qr) * NH + h) * RV + r];
        }
    }
    __syncthreads();

    // Phase A: scores for all 2048 keys
    for (int k = tid; k < S; k += 256) {
        float acc[QT] = {};
        const float4* kp4 = (const float4*)(Km + k * H + h * DH);
        #pragma unroll
        for (int d4 = 0; d4 < DH / 4; ++d4) {
            float4 kv = kp4[d4];
            #pragma unroll
            for (int qi = 0; qi < QT; ++qi) {
                acc[qi] += Qs[qi][d4 * 4 + 0] * kv.x;
                acc[qi] += Qs[qi][d4 * 4 + 1] * kv.y;
                acc[qi] += Qs[qi][d4 * 4 + 2] * kv.z;
                acc[qi] += Qs[qi][d4 * 4 + 3] * kv.w;
            }
        }
        #pragma unroll
        for (int qi = 0; qi < QT; ++qi) {
            int rid = rel_ids[(q0 + qi) * S + k];
            int msk = att_mask[(q0 + qi) * S + k];
            float sc = (acc[qi] + Rl[qi][rid]) * 0.125f;   // 1/sqrt(64)
            sc += -10000.0f * (1.0f - (float)msk);
            Sc[qi][k] = sc;
        }
    }
    __syncthreads();

    // Phase B: softmax, wave w owns row w
    const int w = tid >> 6, lane = tid & 63;
    {
        float m = -1e30f;
        for (int k = lane; k < S; k += 64) m = fmaxf(m, Sc[w][k]);
        #pragma unroll
        for (int off = 32; off > 0; off >>= 1) m = fmaxf(m, __shfl_xor(m, off, 64));
        float s = 0.f;
        for (int k = lane; k < S; k += 64) {
            float e = __expf(Sc[w][k] - m);
            Sc[w][k] = e;
            s += e;
        }
        #pragma unroll
        for (int off = 32; off > 0; off >>= 1) s += __shfl_xor(s, off, 64);
        float inv = 1.0f / s;
        for (int k = lane; k < S; k += 64) Sc[w][k] *= inv;
    }
    // no sync needed: wave w reads only row w below

    // Phase C: ctx[q0+w, h, d=lane] = sum_k P[w][k] * V[k,h,d]
    {
        float acc = 0.f;
        const float* vcol = Vm + h * DH + lane;
        for (int k = 0; k < S; ++k) acc += Sc[w][k] * vcol[k * H];
        ctx[(q0 + w) * H + h * DH + lane] = acc;
    }
}

// ---------------- output GEMM: out = ctx(fp32) @ Wo + bo -------------------
__global__ __launch_bounds__(256) void out_gemm(
    const float* __restrict__ Am, const void* __restrict__ W,
    const void* __restrict__ bias, void* __restrict__ out,
    const int* __restrict__ flag)
{
    __shared__ float As[16][65];
    __shared__ float Bs[16][65];
    const int tid = threadIdx.x;
    const int f = *flag;
    const int tx = tid & 15, ty = tid >> 4;
    const int rowb = blockIdx.y * 64;
    const int colb = blockIdx.x * 64;

    float acc[4][4] = {};
    for (int kb = 0; kb < H; kb += 16) {
        #pragma unroll
        for (int i = tid; i < 1024; i += 256) {
            int m = i >> 4, kk = i & 15;
            As[kk][m] = Am[(rowb + m) * H + kb + kk];
        }
        #pragma unroll
        for (int i = tid; i < 1024; i += 256) {
            int n = i & 63, kk = i >> 6;
            Bs[kk][n] = ldf(W, (kb + kk) * H + colb + n, f);
        }
        __syncthreads();
        #pragma unroll
        for (int kk = 0; kk < 16; ++kk) {
            float a[4], b[4];
            #pragma unroll
            for (int i = 0; i < 4; ++i) a[i] = As[kk][ty * 4 + i];
            #pragma unroll
            for (int j = 0; j < 4; ++j) b[j] = Bs[kk][tx * 4 + j];
            #pragma unroll
            for (int i = 0; i < 4; ++i)
                #pragma unroll
                for (int j = 0; j < 4; ++j)
                    acc[i][j] += a[i] * b[j];
        }
        __syncthreads();
    }
    #pragma unroll
    for (int i = 0; i < 4; ++i) {
        int m = rowb + ty * 4 + i;
        #pragma unroll
        for (int j = 0; j < 4; ++j) {
            int n = colb + tx * 4 + j;
            float v = acc[i][j] + ldf(bias, n, f);
            if (f) ((float*)out)[m * H + n] = v;
            else   ((bf16*)out)[m * H + n] = __float2bfloat16(v);
        }
    }
}

extern "C" void kernel_launch(void* const* d_in, const int* in_sizes, int n_in,
                              void* d_out, int out_size, void* d_ws, size_t ws_size,
                              hipStream_t stream)
{
    const void* x        = d_in[0];
    const int*  att_mask = (const int*)d_in[1];
    const int*  rel_ids  = (const int*)d_in[2];
    const void* Wq = d_in[3];
    const void* bq = d_in[4];
    const void* Wk = d_in[5];
    const void* bk = d_in[6];
    const void* Wv = d_in[7];
    const void* bv = d_in[8];
    const void* rel_emb  = d_in[9];
    const void* rel_bias = d_in[10];
    const void* Wo = d_in[11];
    const void* bo = d_in[12];

    float* ws = (float*)d_ws;
    float* Qw = ws;                 // S*H
    float* Kw = Qw + (size_t)S * H; // S*H
    float* Vw = Kw + (size_t)S * H; // S*H
    float* Cw = Vw + (size_t)S * H; // S*H (ctx)
    float* Rw = Cw + (size_t)S * H; // S*NH*RV (all_rel)
    int*  flag = (int*)(Rw + (size_t)S * NH * RV);

    detect_dtype<<<1, 256, 0, stream>>>((const unsigned int*)x, flag);

    dim3 g1(H / 64, S / 64, 3);
    qkv_gemm<<<g1, 256, 0, stream>>>(x, Wq, bq, Wk, bk, Wv, bv, Qw, Kw, Vw, flag);

    rel_scores_kernel<<<dim3(S), 256, 0, stream>>>(Qw, rel_emb, rel_bias, Rw, flag);

    dim3 g3(S / QT, NH);
    attn_kernel<<<g3, 256, 0, stream>>>(Qw, Kw, Vw, Rw, att_mask, rel_ids, Cw);

    dim3 g4(H / 64, S / 64);
    out_gemm<<<g4, 256, 0, stream>>>(Cw, Wo, bo, d_out, flag);
}

// Round 3
// 1035.570 us; speedup vs baseline: 3.1783x; 3.1783x over previous
//
#include <hip/hip_runtime.h>
#include <hip/hip_bf16.h>

#define S 2048
#define H 1024
#define NH 16
#define DH 64
#define RV 32

typedef __hip_bfloat16 bf16;
typedef short bf16x8 __attribute__((ext_vector_type(8)));
typedef float f32x4 __attribute__((ext_vector_type(4)));

__device__ __forceinline__ float b2f(bf16 v) { return __bfloat162float(v); }
__device__ __forceinline__ unsigned short f2bbits(float x) {
    __hip_bfloat16 b = __float2bfloat16(x);
    return *reinterpret_cast<unsigned short*>(&b);
}

// Flexible load: f==1 -> buffer holds fp32, f==0 -> buffer holds bf16.
__device__ __forceinline__ float ldf(const void* p, int i, int f) {
    return f ? ((const float*)p)[i] : b2f(((const bf16*)p)[i]);
}

// ---------------- dtype sniffer -------------------------------------------
__global__ void detect_dtype(const unsigned int* __restrict__ xw,
                             int* __restrict__ flag)
{
    __shared__ int cnt;
    if (threadIdx.x == 0) cnt = 0;
    __syncthreads();
    unsigned int w = xw[threadIdx.x];
    unsigned int ex = ((w & 0xffffu) >> 7) & 0xffu;
    int big = (ex > 134u) ? 1 : 0;
    #pragma unroll
    for (int off = 32; off > 0; off >>= 1) big += __shfl_xor(big, off, 64);
    if ((threadIdx.x & 63) == 0) atomicAdd(&cnt, big);
    __syncthreads();
    if (threadIdx.x == 0) *flag = (cnt > 60) ? 1 : 0;
}

// ---------------- QKV GEMM -------------------------------------------------
// 64x64 tile, BK=16, 256 threads, 4x4/thread. z=0: Q (fp32 + bf16),
// z=1: K (bf16), z=2: V (bf16, TRANSPOSED to [H][S] for attention B-frags).
__global__ __launch_bounds__(256) void qkv_gemm(
    const void* __restrict__ x,
    const void* __restrict__ Wq, const void* __restrict__ bq,
    const void* __restrict__ Wk, const void* __restrict__ bk,
    const void* __restrict__ Wv, const void* __restrict__ bv,
    float* __restrict__ Qw, bf16* __restrict__ Qb,
    bf16* __restrict__ Kb, bf16* __restrict__ VT,
    const int* __restrict__ flag)
{
    const void* W; const void* bias;
    if (blockIdx.z == 0)      { W = Wq; bias = bq; }
    else if (blockIdx.z == 1) { W = Wk; bias = bk; }
    else                      { W = Wv; bias = bv; }
    const int f = *flag;

    __shared__ float As[16][65];   // [k][m]
    __shared__ float Bs[16][65];   // [k][n]
    const int tid = threadIdx.x;
    const int tx = tid & 15, ty = tid >> 4;
    const int rowb = blockIdx.y * 64;
    const int colb = blockIdx.x * 64;

    float acc[4][4] = {};
    for (int kb = 0; kb < H; kb += 16) {
        #pragma unroll
        for (int i = tid; i < 1024; i += 256) {
            int m = i >> 4, kk = i & 15;
            As[kk][m] = ldf(x, (rowb + m) * H + kb + kk, f);
        }
        #pragma unroll
        for (int i = tid; i < 1024; i += 256) {
            int n = i & 63, kk = i >> 6;
            Bs[kk][n] = ldf(W, (kb + kk) * H + colb + n, f);
        }
        __syncthreads();
        #pragma unroll
        for (int kk = 0; kk < 16; ++kk) {
            float a[4], b[4];
            #pragma unroll
            for (int i = 0; i < 4; ++i) a[i] = As[kk][ty * 4 + i];
            #pragma unroll
            for (int j = 0; j < 4; ++j) b[j] = Bs[kk][tx * 4 + j];
            #pragma unroll
            for (int i = 0; i < 4; ++i)
                #pragma unroll
                for (int j = 0; j < 4; ++j)
                    acc[i][j] += a[i] * b[j];
        }
        __syncthreads();
    }

    if (blockIdx.z == 2) {
        // transposed bf16 store: VT[n][token], 4 consecutive tokens -> ushort4
        #pragma unroll
        for (int j = 0; j < 4; ++j) {
            int n = colb + tx * 4 + j;
            float bv_ = ldf(bias, n, f);
            ushort4 pack;
            unsigned short* ps = (unsigned short*)&pack;
            #pragma unroll
            for (int i = 0; i < 4; ++i) ps[i] = f2bbits(acc[i][j] + bv_);
            *(ushort4*)&VT[(size_t)n * S + rowb + ty * 4] = pack;
        }
    } else if (blockIdx.z == 1) {
        #pragma unroll
        for (int i = 0; i < 4; ++i) {
            int m = rowb + ty * 4 + i;
            #pragma unroll
            for (int j = 0; j < 4; ++j) {
                int n = colb + tx * 4 + j;
                Kb[m * H + n] = __float2bfloat16(acc[i][j] + ldf(bias, n, f));
            }
        }
    } else {
        #pragma unroll
        for (int i = 0; i < 4; ++i) {
            int m = rowb + ty * 4 + i;
            #pragma unroll
            for (int j = 0; j < 4; ++j) {
                int n = colb + tx * 4 + j;
                float v = acc[i][j] + ldf(bias, n, f);
                Qw[m * H + n] = v;
                Qb[m * H + n] = __float2bfloat16(v);
            }
        }
    }
}

// ---------------- all_rel[q][h][r] = Q[q,h,:] . rel_emb[r,h,:] + rel_bias[r,h]
__global__ __launch_bounds__(256) void rel_scores_kernel(
    const float* __restrict__ Q, const void* __restrict__ rel_emb,
    const void* __restrict__ rel_bias, float* __restrict__ Rel,
    const int* __restrict__ flag)
{
    const int q = blockIdx.x;
    const int f = *flag;
    __shared__ float Qs[H];
    for (int i = threadIdx.x; i < H; i += 256) Qs[i] = Q[q * H + i];
    __syncthreads();
    for (int p = threadIdx.x; p < NH * RV; p += 256) {
        int h = p >> 5;
        int r = p & 31;
        const float* qs = Qs + h * DH;
        float acc = 0.f;
        #pragma unroll
        for (int d = 0; d < DH; ++d) acc += qs[d] * ldf(rel_emb, (r * NH + h) * DH + d, f);
        Rel[(q * NH + h) * RV + r] = acc + ldf(rel_bias, r * NH + h, f);
    }
}

// ---------------- MFMA flash attention ------------------------------------
// block = (64 queries) x (1 head), 4 waves; wave w owns q rows w*16..w*16+15.
// K-loop over 32 tiles of 64 keys. QK^T and P.V via mfma 16x16x32 bf16.
__global__ __launch_bounds__(256) void attn_mfma(
    const bf16* __restrict__ Qb, const bf16* __restrict__ Kb,
    const bf16* __restrict__ VT, const float* __restrict__ Rel,
    const int* __restrict__ att_mask, const int* __restrict__ rel_ids,
    float* __restrict__ ctx)
{
    const int h = blockIdx.y;
    const int q0 = blockIdx.x * 64;
    const int tid = threadIdx.x;
    const int w = tid >> 6;
    const int lane = tid & 63;
    const int l15 = lane & 15;
    const int quad = lane >> 4;

    __shared__ short Qs[64][72];   // [q][d], pad to 144B rows (bank spread)
    __shared__ short Ks[64][72];   // [key][d]
    __shared__ short Vs[64][72];   // [d][key]  (from pre-transposed VT)
    __shared__ short Ps[64][72];   // [q][key]
    __shared__ float Bias[64][64]; // rel*0.125 + mask term, per k-tile
    __shared__ float Rl[64][33];   // rel table, padded for gather spread

    // stage Q tile + Rel table once
    for (int slot = tid; slot < 512; slot += 256) {
        int q = slot >> 3, c = slot & 7;
        *(uint4*)&Qs[q][c * 8] = *(const uint4*)&Qb[(q0 + q) * H + h * DH + c * 8];
    }
    for (int i = tid; i < 64 * RV; i += 256) {
        int q = i >> 5, r = i & 31;
        Rl[q][r] = Rel[((q0 + q) * NH + h) * RV + r];
    }
    __syncthreads();

    f32x4 O[4];
    float mrow[4], lrow[4];
    #pragma unroll
    for (int i = 0; i < 4; ++i) { O[i] = (f32x4)0.f; mrow[i] = -1e30f; lrow[i] = 0.f; }

    for (int kt = 0; kt < S; kt += 64) {
        // ---- stage K, V(transposed), Bias tiles ----
        for (int slot = tid; slot < 512; slot += 256) {
            int r = slot >> 3, c = slot & 7;
            *(uint4*)&Ks[r][c * 8] = *(const uint4*)&Kb[(kt + r) * H + h * DH + c * 8];
            *(uint4*)&Vs[r][c * 8] = *(const uint4*)&VT[(size_t)(h * DH + r) * S + kt + c * 8];
        }
        {
            int q = tid >> 2, kg = (tid & 3) * 16;
            const int* ridp = rel_ids + (q0 + q) * S + kt + kg;
            const int* mskp = att_mask + (q0 + q) * S + kt + kg;
            #pragma unroll
            for (int kk = 0; kk < 16; ++kk) {
                int rid = ridp[kk];
                int msk = mskp[kk];
                Bias[q][kg + kk] = Rl[q][rid] * 0.125f - 10000.0f * (1.0f - (float)msk);
            }
        }
        __syncthreads();

        // ---- QK^T: rows w*16..+15, all 64 keys ----
        bf16x8 aq0 = *(const bf16x8*)&Qs[w * 16 + l15][quad * 8];
        bf16x8 aq1 = *(const bf16x8*)&Qs[w * 16 + l15][32 + quad * 8];
        f32x4 sc[4];
        #pragma unroll
        for (int nt = 0; nt < 4; ++nt) {
            bf16x8 bk0 = *(const bf16x8*)&Ks[nt * 16 + l15][quad * 8];
            bf16x8 bk1 = *(const bf16x8*)&Ks[nt * 16 + l15][32 + quad * 8];
            f32x4 c = (f32x4)0.f;
            c = __builtin_amdgcn_mfma_f32_16x16x32_bf16(aq0, bk0, c, 0, 0, 0);
            c = __builtin_amdgcn_mfma_f32_16x16x32_bf16(aq1, bk1, c, 0, 0, 0);
            sc[nt] = c;
        }
        // scale + rel/mask bias (C layout: row = quad*4+r, col = l15)
        #pragma unroll
        for (int nt = 0; nt < 4; ++nt)
            #pragma unroll
            for (int r = 0; r < 4; ++r)
                sc[nt][r] = sc[nt][r] * 0.125f + Bias[w * 16 + quad * 4 + r][nt * 16 + l15];

        // ---- online softmax over this k-tile ----
        float alpha[4];
        #pragma unroll
        for (int r = 0; r < 4; ++r) {
            float v = fmaxf(fmaxf(sc[0][r], sc[1][r]), fmaxf(sc[2][r], sc[3][r]));
            v = fmaxf(v, __shfl_xor(v, 1, 64));
            v = fmaxf(v, __shfl_xor(v, 2, 64));
            v = fmaxf(v, __shfl_xor(v, 4, 64));
            v = fmaxf(v, __shfl_xor(v, 8, 64));
            float mnew = fmaxf(mrow[r], v);
            alpha[r] = __expf(mrow[r] - mnew);
            mrow[r] = mnew;
        }
        float rsum[4] = {0.f, 0.f, 0.f, 0.f};
        #pragma unroll
        for (int nt = 0; nt < 4; ++nt)
            #pragma unroll
            for (int r = 0; r < 4; ++r) {
                float p = __expf(sc[nt][r] - mrow[r]);
                sc[nt][r] = p;
                rsum[r] += p;
            }
        #pragma unroll
        for (int r = 0; r < 4; ++r) {
            float v = rsum[r];
            v += __shfl_xor(v, 1, 64);
            v += __shfl_xor(v, 2, 64);
            v += __shfl_xor(v, 4, 64);
            v += __shfl_xor(v, 8, 64);
            lrow[r] = lrow[r] * alpha[r] + v;
            #pragma unroll
            for (int dt = 0; dt < 4; ++dt) O[dt][r] *= alpha[r];
        }

        // ---- P -> LDS (wave-private rows; no barrier needed) ----
        #pragma unroll
        for (int nt = 0; nt < 4; ++nt)
            #pragma unroll
            for (int r = 0; r < 4; ++r)
                ((unsigned short*)&Ps[w * 16 + quad * 4 + r][nt * 16 + l15])[0] = f2bbits(sc[nt][r]);

        // ---- P.V accumulate ----
        bf16x8 ap0 = *(const bf16x8*)&Ps[w * 16 + l15][quad * 8];
        bf16x8 ap1 = *(const bf16x8*)&Ps[w * 16 + l15][32 + quad * 8];
        #pragma unroll
        for (int dt = 0; dt < 4; ++dt) {
            bf16x8 bv0 = *(const bf16x8*)&Vs[dt * 16 + l15][quad * 8];
            bf16x8 bv1 = *(const bf16x8*)&Vs[dt * 16 + l15][32 + quad * 8];
            O[dt] = __builtin_amdgcn_mfma_f32_16x16x32_bf16(ap0, bv0, O[dt], 0, 0, 0);
            O[dt] = __builtin_amdgcn_mfma_f32_16x16x32_bf16(ap1, bv1, O[dt], 0, 0, 0);
        }
        __syncthreads();   // guard tile restage against this iteration's reads
    }

    // ---- epilogue: O / l -> ctx fp32 ----
    #pragma unroll
    for (int r = 0; r < 4; ++r) {
        int q = q0 + w * 16 + quad * 4 + r;
        float inv = 1.0f / lrow[r];
        #pragma unroll
        for (int dt = 0; dt < 4; ++dt)
            ctx[q * H + h * DH + dt * 16 + l15] = O[dt][r] * inv;
    }
}

// ---------------- output GEMM: out = ctx(fp32) @ Wo + bo -------------------
__global__ __launch_bounds__(256) void out_gemm(
    const float* __restrict__ Am, const void* __restrict__ W,
    const void* __restrict__ bias, void* __restrict__ out,
    const int* __restrict__ flag)
{
    __shared__ float As[16][65];
    __shared__ float Bs[16][65];
    const int tid = threadIdx.x;
    const int f = *flag;
    const int tx = tid & 15, ty = tid >> 4;
    const int rowb = blockIdx.y * 64;
    const int colb = blockIdx.x * 64;

    float acc[4][4] = {};
    for (int kb = 0; kb < H; kb += 16) {
        #pragma unroll
        for (int i = tid; i < 1024; i += 256) {
            int m = i >> 4, kk = i & 15;
            As[kk][m] = Am[(rowb + m) * H + kb + kk];
        }
        #pragma unroll
        for (int i = tid; i < 1024; i += 256) {
            int n = i & 63, kk = i >> 6;
            Bs[kk][n] = ldf(W, (kb + kk) * H + colb + n, f);
        }
        __syncthreads();
        #pragma unroll
        for (int kk = 0; kk < 16; ++kk) {
            float a[4], b[4];
            #pragma unroll
            for (int i = 0; i < 4; ++i) a[i] = As[kk][ty * 4 + i];
            #pragma unroll
            for (int j = 0; j < 4; ++j) b[j] = Bs[kk][tx * 4 + j];
            #pragma unroll
            for (int i = 0; i < 4; ++i)
                #pragma unroll
                for (int j = 0; j < 4; ++j)
                    acc[i][j] += a[i] * b[j];
        }
        __syncthreads();
    }
    #pragma unroll
    for (int i = 0; i < 4; ++i) {
        int m = rowb + ty * 4 + i;
        #pragma unroll
        for (int j = 0; j < 4; ++j) {
            int n = colb + tx * 4 + j;
            float v = acc[i][j] + ldf(bias, n, f);
            if (f) ((float*)out)[m * H + n] = v;
            else   ((bf16*)out)[m * H + n] = __float2bfloat16(v);
        }
    }
}

extern "C" void kernel_launch(void* const* d_in, const int* in_sizes, int n_in,
                              void* d_out, int out_size, void* d_ws, size_t ws_size,
                              hipStream_t stream)
{
    const void* x        = d_in[0];
    const int*  att_mask = (const int*)d_in[1];
    const int*  rel_ids  = (const int*)d_in[2];
    const void* Wq = d_in[3];
    const void* bq = d_in[4];
    const void* Wk = d_in[5];
    const void* bk = d_in[6];
    const void* Wv = d_in[7];
    const void* bv = d_in[8];
    const void* rel_emb  = d_in[9];
    const void* rel_bias = d_in[10];
    const void* Wo = d_in[11];
    const void* bo = d_in[12];

    char* ws = (char*)d_ws;
    float* Qw = (float*)ws;                      ws += (size_t)S * H * 4;
    float* Cw = (float*)ws;                      ws += (size_t)S * H * 4;
    float* Rw = (float*)ws;                      ws += (size_t)S * NH * RV * 4;
    bf16*  Qb = (bf16*)ws;                       ws += (size_t)S * H * 2;
    bf16*  Kb = (bf16*)ws;                       ws += (size_t)S * H * 2;
    bf16*  VT = (bf16*)ws;                       ws += (size_t)S * H * 2;
    int*  flag = (int*)ws;

    detect_dtype<<<1, 256, 0, stream>>>((const unsigned int*)x, flag);

    dim3 g1(H / 64, S / 64, 3);
    qkv_gemm<<<g1, 256, 0, stream>>>(x, Wq, bq, Wk, bk, Wv, bv,
                                     Qw, Qb, Kb, VT, flag);

    rel_scores_kernel<<<dim3(S), 256, 0, stream>>>(Qw, rel_emb, rel_bias, Rw, flag);

    dim3 g3(S / 64, NH);
    attn_mfma<<<g3, 256, 0, stream>>>(Qb, Kb, VT, Rw, att_mask, rel_ids, Cw);

    dim3 g4(H / 64, S / 64);
    out_gemm<<<g4, 256, 0, stream>>>(Cw, Wo, bo, d_out, flag);
}

// Round 4
// 457.249 us; speedup vs baseline: 7.1981x; 2.2648x over previous
//
#include <hip/hip_runtime.h>
#include <hip/hip_bf16.h>

#define S 2048
#define H 1024
#define NH 16
#define DH 64
#define RV 32
#define BK 32

typedef __hip_bfloat16 bf16;
typedef short bf16x8 __attribute__((ext_vector_type(8)));
typedef float f32x4 __attribute__((ext_vector_type(4)));

__device__ __forceinline__ float b2f(bf16 v) { return __bfloat162float(v); }
__device__ __forceinline__ unsigned short f2bbits(float x) {
    __hip_bfloat16 b = __float2bfloat16(x);
    return *reinterpret_cast<unsigned short*>(&b);
}
// Flexible load: f==1 -> buffer holds fp32, f==0 -> buffer holds bf16.
__device__ __forceinline__ float ldf(const void* p, int i, int f) {
    return f ? ((const float*)p)[i] : b2f(((const bf16*)p)[i]);
}
// async 16B global -> LDS (lane l lands at lds_base + l*16)
__device__ __forceinline__ void gl_lds16(const bf16* g, bf16* l) {
    __builtin_amdgcn_global_load_lds(
        (const __attribute__((address_space(1))) void*)g,
        (__attribute__((address_space(3))) void*)l,
        16, 0, 0);
}

// ---------------- dtype sniffer -------------------------------------------
__global__ void detect_dtype(const unsigned int* __restrict__ xw,
                             int* __restrict__ flag)
{
    __shared__ int cnt;
    if (threadIdx.x == 0) cnt = 0;
    __syncthreads();
    unsigned int w = xw[threadIdx.x];
    unsigned int ex = ((w & 0xffffu) >> 7) & 0xffu;
    int big = (ex > 134u) ? 1 : 0;
    #pragma unroll
    for (int off = 32; off > 0; off >>= 1) big += __shfl_xor(big, off, 64);
    if ((threadIdx.x & 63) == 0) atomicAdd(&cnt, big);
    __syncthreads();
    if (threadIdx.x == 0) *flag = (cnt > 60) ? 1 : 0;
}

// ---------------- input conversion ----------------------------------------
__global__ __launch_bounds__(256) void convert_x(
    const void* __restrict__ x, bf16* __restrict__ xb,
    const int* __restrict__ flag)
{
    const int i = (blockIdx.x * 256 + threadIdx.x) * 4;
    if (*flag) {
        float4 v = ((const float4*)x)[i >> 2];
        ushort4 o;
        o.x = f2bbits(v.x); o.y = f2bbits(v.y);
        o.z = f2bbits(v.z); o.w = f2bbits(v.w);
        *(ushort4*)&xb[i] = o;
    } else {
        ((ushort4*)xb)[i >> 2] = ((const ushort4*)x)[i >> 2];
    }
}

// transpose-convert weights: W[k][n] (fp32 or bf16) -> WT[n][k] bf16
__global__ __launch_bounds__(256) void wtrans(
    const void* __restrict__ W0, const void* __restrict__ W1,
    const void* __restrict__ W2, const void* __restrict__ W3,
    bf16* __restrict__ T0, bf16* __restrict__ T1,
    bf16* __restrict__ T2, bf16* __restrict__ T3,
    const int* __restrict__ flag)
{
    const void* W; bf16* T;
    switch (blockIdx.z) {
        case 0:  W = W0; T = T0; break;
        case 1:  W = W1; T = T1; break;
        case 2:  W = W2; T = T2; break;
        default: W = W3; T = T3; break;
    }
    const int f = *flag;
    __shared__ unsigned short Ts[64][68];
    const int t = threadIdx.x;
    const int tx = t & 15, ty = t >> 4;
    const int n0 = blockIdx.x * 64;
    const int k0 = blockIdx.y * 64;
    #pragma unroll
    for (int it = 0; it < 4; ++it) {
        int k = ty + it * 16;
        int base = (k0 + k) * H + n0 + tx * 4;
        #pragma unroll
        for (int e = 0; e < 4; ++e)
            Ts[k][tx * 4 + e] = f2bbits(ldf(W, base + e, f));
    }
    __syncthreads();
    #pragma unroll
    for (int it = 0; it < 4; ++it) {
        int n = ty + it * 16;
        ushort4 o;
        o.x = Ts[tx * 4 + 0][n];
        o.y = Ts[tx * 4 + 1][n];
        o.z = Ts[tx * 4 + 2][n];
        o.w = Ts[tx * 4 + 3][n];
        *(ushort4*)&T[(size_t)(n0 + n) * H + k0 + tx * 4] = o;
    }
}

// transpose Vb[S][H] bf16 -> VT[H][S] bf16
__global__ __launch_bounds__(256) void vtrans(
    const bf16* __restrict__ Vb, bf16* __restrict__ VT)
{
    __shared__ unsigned short Ts[64][68];
    const int t = threadIdx.x;
    const int tx = t & 15, ty = t >> 4;
    const int s0 = blockIdx.x * 64;
    const int h0 = blockIdx.y * 64;
    #pragma unroll
    for (int it = 0; it < 4; ++it) {
        int s = ty + it * 16;
        *(ushort4*)&Ts[s][tx * 4] =
            *(const ushort4*)&Vb[(size_t)(s0 + s) * H + h0 + tx * 4];
    }
    __syncthreads();
    #pragma unroll
    for (int it = 0; it < 4; ++it) {
        int hh = ty + it * 16;
        ushort4 o;
        o.x = Ts[tx * 4 + 0][hh];
        o.y = Ts[tx * 4 + 1][hh];
        o.z = Ts[tx * 4 + 2][hh];
        o.w = Ts[tx * 4 + 3][hh];
        *(ushort4*)&VT[(size_t)(h0 + hh) * S + s0 + tx * 4] = o;
    }
}

// ---------------- m97-style 128x128 MFMA GEMM core -------------------------
// C[m][n] = sum_k A[m][k] * BT[n][k].  4 waves 2x2, each 64x64 (4x4 mfma tiles).
__device__ __forceinline__ void gemm128_bt(
    const bf16* __restrict__ A, const bf16* __restrict__ BT,
    f32x4 (&acc)[4][4])
{
    const int tid = threadIdx.x;
    const int w = tid >> 6, lane = tid & 63;
    const int l15 = lane & 15, quad = lane >> 4;
    const int wm = (w & 1) * 64, wn = (w >> 1) * 64;
    const int rowb = blockIdx.y * 128;
    const int colb = blockIdx.x * 128;

    __shared__ bf16 As[128 * BK];   // [m][k], rows of 32 bf16 (64 B)
    __shared__ bf16 Bs[128 * BK];   // [n][k]

    for (int kb = 0; kb < H; kb += BK) {
        #pragma unroll
        for (int j = 0; j < 2; ++j) {
            int i = j * 256 + w * 64 + lane;
            gl_lds16(&A[(size_t)(rowb + (i >> 2)) * H + kb + (i & 3) * 8],
                     &As[(size_t)(j * 256 + w * 64) * 8]);
            gl_lds16(&BT[(size_t)(colb + (i >> 2)) * H + kb + (i & 3) * 8],
                     &Bs[(size_t)(j * 256 + w * 64) * 8]);
        }
        __syncthreads();   // drains vmcnt (compiler) + lgkm

        bf16x8 af[4], bfr[4];
        #pragma unroll
        for (int mt = 0; mt < 4; ++mt)
            af[mt] = *(const bf16x8*)&As[(wm + mt * 16 + l15) * BK + quad * 8];
        #pragma unroll
        for (int nt = 0; nt < 4; ++nt)
            bfr[nt] = *(const bf16x8*)&Bs[(wn + nt * 16 + l15) * BK + quad * 8];
        #pragma unroll
        for (int mt = 0; mt < 4; ++mt)
            #pragma unroll
            for (int nt = 0; nt < 4; ++nt)
                acc[mt][nt] = __builtin_amdgcn_mfma_f32_16x16x32_bf16(
                    af[mt], bfr[nt], acc[mt][nt], 0, 0, 0);
        __syncthreads();   // guard next-iter restage vs this iter's reads
    }
}

// ---------------- QKV MFMA GEMM -------------------------------------------
__global__ __launch_bounds__(256) void qkv_mfma(
    const bf16* __restrict__ xb,
    const bf16* __restrict__ WTq, const bf16* __restrict__ WTk,
    const bf16* __restrict__ WTv,
    const void* __restrict__ bq, const void* __restrict__ bk,
    const void* __restrict__ bv,
    bf16* __restrict__ Qb, bf16* __restrict__ Kb, bf16* __restrict__ Vb,
    const int* __restrict__ flag)
{
    const bf16* BT; const void* bias; bf16* out;
    if (blockIdx.z == 0)      { BT = WTq; bias = bq; out = Qb; }
    else if (blockIdx.z == 1) { BT = WTk; bias = bk; out = Kb; }
    else                      { BT = WTv; bias = bv; out = Vb; }
    const int f = *flag;

    f32x4 acc[4][4];
    #pragma unroll
    for (int a = 0; a < 4; ++a)
        #pragma unroll
        for (int b = 0; b < 4; ++b) acc[a][b] = (f32x4)0.f;

    gemm128_bt(xb, BT, acc);

    const int tid = threadIdx.x;
    const int w = tid >> 6, lane = tid & 63;
    const int l15 = lane & 15, quad = lane >> 4;
    const int wm = (w & 1) * 64, wn = (w >> 1) * 64;
    const int rowb = blockIdx.y * 128;
    const int colb = blockIdx.x * 128;

    float bvv[4];
    #pragma unroll
    for (int nt = 0; nt < 4; ++nt)
        bvv[nt] = ldf(bias, colb + wn + nt * 16 + l15, f);

    #pragma unroll
    for (int mt = 0; mt < 4; ++mt)
        #pragma unroll
        for (int nt = 0; nt < 4; ++nt)
            #pragma unroll
            for (int r = 0; r < 4; ++r) {
                int m = rowb + wm + mt * 16 + quad * 4 + r;
                int n = colb + wn + nt * 16 + l15;
                out[(size_t)m * H + n] = __float2bfloat16(acc[mt][nt][r] + bvv[nt]);
            }
}

// ---------------- output MFMA GEMM ----------------------------------------
__global__ __launch_bounds__(256) void out_mfma(
    const bf16* __restrict__ Cb, const bf16* __restrict__ WoT,
    const void* __restrict__ bias, void* __restrict__ out,
    const int* __restrict__ flag)
{
    const int f = *flag;
    f32x4 acc[4][4];
    #pragma unroll
    for (int a = 0; a < 4; ++a)
        #pragma unroll
        for (int b = 0; b < 4; ++b) acc[a][b] = (f32x4)0.f;

    gemm128_bt(Cb, WoT, acc);

    const int tid = threadIdx.x;
    const int w = tid >> 6, lane = tid & 63;
    const int l15 = lane & 15, quad = lane >> 4;
    const int wm = (w & 1) * 64, wn = (w >> 1) * 64;
    const int rowb = blockIdx.y * 128;
    const int colb = blockIdx.x * 128;

    float bvv[4];
    #pragma unroll
    for (int nt = 0; nt < 4; ++nt)
        bvv[nt] = ldf(bias, colb + wn + nt * 16 + l15, f);

    #pragma unroll
    for (int mt = 0; mt < 4; ++mt)
        #pragma unroll
        for (int nt = 0; nt < 4; ++nt)
            #pragma unroll
            for (int r = 0; r < 4; ++r) {
                int m = rowb + wm + mt * 16 + quad * 4 + r;
                int n = colb + wn + nt * 16 + l15;
                float v = acc[mt][nt][r] + bvv[nt];
                if (f) ((float*)out)[(size_t)m * H + n] = v;
                else   ((bf16*)out)[(size_t)m * H + n] = __float2bfloat16(v);
            }
}

// ---------------- all_rel[q][h][r] = Q[q,h,:] . rel_emb[r,h,:] + rel_bias[r,h]
__global__ __launch_bounds__(256) void rel_scores_kernel(
    const bf16* __restrict__ Qb, const void* __restrict__ rel_emb,
    const void* __restrict__ rel_bias, float* __restrict__ Rel,
    const int* __restrict__ flag)
{
    const int q = blockIdx.x;
    const int f = *flag;
    __shared__ float Qs[H];
    for (int i = threadIdx.x; i < H; i += 256) Qs[i] = b2f(Qb[q * H + i]);
    __syncthreads();
    for (int p = threadIdx.x; p < NH * RV; p += 256) {
        int h = p >> 5;
        int r = p & 31;
        const float* qs = Qs + h * DH;
        float acc = 0.f;
        #pragma unroll
        for (int d = 0; d < DH; ++d)
            acc += qs[d] * ldf(rel_emb, (r * NH + h) * DH + d, f);
        Rel[(q * NH + h) * RV + r] = acc + ldf(rel_bias, r * NH + h, f);
    }
}

// ---------------- MFMA flash attention ------------------------------------
__global__ __launch_bounds__(256) void attn_mfma(
    const bf16* __restrict__ Qb, const bf16* __restrict__ Kb,
    const bf16* __restrict__ VT, const float* __restrict__ Rel,
    const int* __restrict__ att_mask, const int* __restrict__ rel_ids,
    bf16* __restrict__ Cb)
{
    const int h = blockIdx.y;
    const int q0 = blockIdx.x * 64;
    const int tid = threadIdx.x;
    const int w = tid >> 6;
    const int lane = tid & 63;
    const int l15 = lane & 15;
    const int quad = lane >> 4;

    __shared__ short Qs[64][72];
    __shared__ short Ks[64][72];
    __shared__ short Vs[64][72];
    __shared__ short Ps[64][72];
    __shared__ float Bias[64][64];
    __shared__ float Rl[64][33];

    for (int slot = tid; slot < 512; slot += 256) {
        int q = slot >> 3, c = slot & 7;
        *(uint4*)&Qs[q][c * 8] = *(const uint4*)&Qb[(q0 + q) * H + h * DH + c * 8];
    }
    for (int i = tid; i < 64 * RV; i += 256) {
        int q = i >> 5, r = i & 31;
        Rl[q][r] = Rel[((q0 + q) * NH + h) * RV + r];
    }
    __syncthreads();

    f32x4 O[4];
    float mrow[4], lrow[4];
    #pragma unroll
    for (int i = 0; i < 4; ++i) { O[i] = (f32x4)0.f; mrow[i] = -1e30f; lrow[i] = 0.f; }

    for (int kt = 0; kt < S; kt += 64) {
        for (int slot = tid; slot < 512; slot += 256) {
            int r = slot >> 3, c = slot & 7;
            *(uint4*)&Ks[r][c * 8] = *(const uint4*)&Kb[(kt + r) * H + h * DH + c * 8];
            *(uint4*)&Vs[r][c * 8] = *(const uint4*)&VT[(size_t)(h * DH + r) * S + kt + c * 8];
        }
        {
            int q = tid >> 2, kg = (tid & 3) * 16;
            const int* ridp = rel_ids + (q0 + q) * S + kt + kg;
            const int* mskp = att_mask + (q0 + q) * S + kt + kg;
            #pragma unroll
            for (int kk = 0; kk < 16; ++kk) {
                int rid = ridp[kk];
                int msk = mskp[kk];
                Bias[q][kg + kk] = Rl[q][rid] * 0.125f - 10000.0f * (1.0f - (float)msk);
            }
        }
        __syncthreads();

        bf16x8 aq0 = *(const bf16x8*)&Qs[w * 16 + l15][quad * 8];
        bf16x8 aq1 = *(const bf16x8*)&Qs[w * 16 + l15][32 + quad * 8];
        f32x4 sc[4];
        #pragma unroll
        for (int nt = 0; nt < 4; ++nt) {
            bf16x8 bk0 = *(const bf16x8*)&Ks[nt * 16 + l15][quad * 8];
            bf16x8 bk1 = *(const bf16x8*)&Ks[nt * 16 + l15][32 + quad * 8];
            f32x4 c = (f32x4)0.f;
            c = __builtin_amdgcn_mfma_f32_16x16x32_bf16(aq0, bk0, c, 0, 0, 0);
            c = __builtin_amdgcn_mfma_f32_16x16x32_bf16(aq1, bk1, c, 0, 0, 0);
            sc[nt] = c;
        }
        #pragma unroll
        for (int nt = 0; nt < 4; ++nt)
            #pragma unroll
            for (int r = 0; r < 4; ++r)
                sc[nt][r] = sc[nt][r] * 0.125f + Bias[w * 16 + quad * 4 + r][nt * 16 + l15];

        float alpha[4];
        #pragma unroll
        for (int r = 0; r < 4; ++r) {
            float v = fmaxf(fmaxf(sc[0][r], sc[1][r]), fmaxf(sc[2][r], sc[3][r]));
            v = fmaxf(v, __shfl_xor(v, 1, 64));
            v = fmaxf(v, __shfl_xor(v, 2, 64));
            v = fmaxf(v, __shfl_xor(v, 4, 64));
            v = fmaxf(v, __shfl_xor(v, 8, 64));
            float mnew = fmaxf(mrow[r], v);
            alpha[r] = __expf(mrow[r] - mnew);
            mrow[r] = mnew;
        }
        float rsum[4] = {0.f, 0.f, 0.f, 0.f};
        #pragma unroll
        for (int nt = 0; nt < 4; ++nt)
            #pragma unroll
            for (int r = 0; r < 4; ++r) {
                float p = __expf(sc[nt][r] - mrow[r]);
                sc[nt][r] = p;
                rsum[r] += p;
            }
        #pragma unroll
        for (int r = 0; r < 4; ++r) {
            float v = rsum[r];
            v += __shfl_xor(v, 1, 64);
            v += __shfl_xor(v, 2, 64);
            v += __shfl_xor(v, 4, 64);
            v += __shfl_xor(v, 8, 64);
            lrow[r] = lrow[r] * alpha[r] + v;
            #pragma unroll
            for (int dt = 0; dt < 4; ++dt) O[dt][r] *= alpha[r];
        }

        #pragma unroll
        for (int nt = 0; nt < 4; ++nt)
            #pragma unroll
            for (int r = 0; r < 4; ++r)
                ((unsigned short*)&Ps[w * 16 + quad * 4 + r][nt * 16 + l15])[0] = f2bbits(sc[nt][r]);

        bf16x8 ap0 = *(const bf16x8*)&Ps[w * 16 + l15][quad * 8];
        bf16x8 ap1 = *(const bf16x8*)&Ps[w * 16 + l15][32 + quad * 8];
        #pragma unroll
        for (int dt = 0; dt < 4; ++dt) {
            bf16x8 bv0 = *(const bf16x8*)&Vs[dt * 16 + l15][quad * 8];
            bf16x8 bv1 = *(const bf16x8*)&Vs[dt * 16 + l15][32 + quad * 8];
            O[dt] = __builtin_amdgcn_mfma_f32_16x16x32_bf16(ap0, bv0, O[dt], 0, 0, 0);
            O[dt] = __builtin_amdgcn_mfma_f32_16x16x32_bf16(ap1, bv1, O[dt], 0, 0, 0);
        }
        __syncthreads();
    }

    #pragma unroll
    for (int r = 0; r < 4; ++r) {
        int q = q0 + w * 16 + quad * 4 + r;
        float inv = 1.0f / lrow[r];
        #pragma unroll
        for (int dt = 0; dt < 4; ++dt)
            Cb[(size_t)q * H + h * DH + dt * 16 + l15] = __float2bfloat16(O[dt][r] * inv);
    }
}

extern "C" void kernel_launch(void* const* d_in, const int* in_sizes, int n_in,
                              void* d_out, int out_size, void* d_ws, size_t ws_size,
                              hipStream_t stream)
{
    const void* x        = d_in[0];
    const int*  att_mask = (const int*)d_in[1];
    const int*  rel_ids  = (const int*)d_in[2];
    const void* Wq = d_in[3];
    const void* bq = d_in[4];
    const void* Wk = d_in[5];
    const void* bk = d_in[6];
    const void* Wv = d_in[7];
    const void* bv = d_in[8];
    const void* rel_emb  = d_in[9];
    const void* rel_bias = d_in[10];
    const void* Wo = d_in[11];
    const void* bo = d_in[12];

    char* p = (char*)d_ws;
    bf16* xb  = (bf16*)p; p += (size_t)S * H * 2;
    bf16* WTq = (bf16*)p; p += (size_t)H * H * 2;
    bf16* WTk = (bf16*)p; p += (size_t)H * H * 2;
    bf16* WTv = (bf16*)p; p += (size_t)H * H * 2;
    bf16* WoT = (bf16*)p; p += (size_t)H * H * 2;
    bf16* Qb  = (bf16*)p; p += (size_t)S * H * 2;
    bf16* Kb  = (bf16*)p; p += (size_t)S * H * 2;
    bf16* Vb  = (bf16*)p; p += (size_t)S * H * 2;
    bf16* VT  = (bf16*)p; p += (size_t)S * H * 2;
    bf16* Cb  = (bf16*)p; p += (size_t)S * H * 2;
    float* Rw = (float*)p; p += (size_t)S * NH * RV * 4;
    int* flag = (int*)p;

    detect_dtype<<<1, 256, 0, stream>>>((const unsigned int*)x, flag);

    convert_x<<<(S * H) / 1024, 256, 0, stream>>>(x, xb, flag);
    wtrans<<<dim3(H / 64, H / 64, 4), 256, 0, stream>>>(
        Wq, Wk, Wv, Wo, WTq, WTk, WTv, WoT, flag);

    qkv_mfma<<<dim3(H / 128, S / 128, 3), 256, 0, stream>>>(
        xb, WTq, WTk, WTv, bq, bk, bv, Qb, Kb, Vb, flag);

    vtrans<<<dim3(S / 64, H / 64), 256, 0, stream>>>(Vb, VT);

    rel_scores_kernel<<<dim3(S), 256, 0, stream>>>(Qb, rel_emb, rel_bias, Rw, flag);

    attn_mfma<<<dim3(S / 64, NH), 256, 0, stream>>>(
        Qb, Kb, VT, Rw, att_mask, rel_ids, Cb);

    out_mfma<<<dim3(H / 128, S / 128), 256, 0, stream>>>(Cb, WoT, bo, d_out, flag);
}

// Round 5
// 272.106 us; speedup vs baseline: 12.0957x; 1.6804x over previous
//
#include <hip/hip_runtime.h>
#include <hip/hip_bf16.h>

#define S 2048
#define H 1024
#define NH 16
#define DH 64
#define RV 32
#define BK 32

typedef __hip_bfloat16 bf16;
typedef short bf16x8 __attribute__((ext_vector_type(8)));
typedef float f32x4 __attribute__((ext_vector_type(4)));

__device__ __forceinline__ float b2f(bf16 v) { return __bfloat162float(v); }
__device__ __forceinline__ unsigned short f2bbits(float x) {
    __hip_bfloat16 b = __float2bfloat16(x);
    return *reinterpret_cast<unsigned short*>(&b);
}
// Flexible load: f==1 -> buffer holds fp32, f==0 -> buffer holds bf16.
__device__ __forceinline__ float ldf(const void* p, int i, int f) {
    return f ? ((const float*)p)[i] : b2f(((const bf16*)p)[i]);
}
// async 16B global -> LDS (lane l lands at lds_base + l*16)
__device__ __forceinline__ void gl_lds16(const bf16* g, bf16* l) {
    __builtin_amdgcn_global_load_lds(
        (const __attribute__((address_space(1))) void*)g,
        (__attribute__((address_space(3))) void*)l,
        16, 0, 0);
}

// ---------------- dtype sniffer -------------------------------------------
__global__ void detect_dtype(const unsigned int* __restrict__ xw,
                             int* __restrict__ flag)
{
    __shared__ int cnt;
    if (threadIdx.x == 0) cnt = 0;
    __syncthreads();
    unsigned int w = xw[threadIdx.x];
    unsigned int ex = ((w & 0xffffu) >> 7) & 0xffu;
    int big = (ex > 134u) ? 1 : 0;
    #pragma unroll
    for (int off = 32; off > 0; off >>= 1) big += __shfl_xor(big, off, 64);
    if ((threadIdx.x & 63) == 0) atomicAdd(&cnt, big);
    __syncthreads();
    if (threadIdx.x == 0) *flag = (cnt > 60) ? 1 : 0;
}

// ---------------- input conversion ----------------------------------------
__global__ __launch_bounds__(256) void convert_x(
    const void* __restrict__ x, bf16* __restrict__ xb,
    const int* __restrict__ flag)
{
    const int i = (blockIdx.x * 256 + threadIdx.x) * 4;
    if (*flag) {
        float4 v = ((const float4*)x)[i >> 2];
        ushort4 o;
        o.x = f2bbits(v.x); o.y = f2bbits(v.y);
        o.z = f2bbits(v.z); o.w = f2bbits(v.w);
        *(ushort4*)&xb[i] = o;
    } else {
        ((ushort4*)xb)[i >> 2] = ((const ushort4*)x)[i >> 2];
    }
}

// transpose-convert weights: W[k][n] (fp32 or bf16) -> WT[n][k] bf16
__global__ __launch_bounds__(256) void wtrans(
    const void* __restrict__ W0, const void* __restrict__ W1,
    const void* __restrict__ W2, const void* __restrict__ W3,
    bf16* __restrict__ T0, bf16* __restrict__ T1,
    bf16* __restrict__ T2, bf16* __restrict__ T3,
    const int* __restrict__ flag)
{
    const void* W; bf16* T;
    switch (blockIdx.z) {
        case 0:  W = W0; T = T0; break;
        case 1:  W = W1; T = T1; break;
        case 2:  W = W2; T = T2; break;
        default: W = W3; T = T3; break;
    }
    const int f = *flag;
    __shared__ unsigned short Ts[64][68];
    const int t = threadIdx.x;
    const int tx = t & 15, ty = t >> 4;
    const int n0 = blockIdx.x * 64;
    const int k0 = blockIdx.y * 64;
    #pragma unroll
    for (int it = 0; it < 4; ++it) {
        int k = ty + it * 16;
        int base = (k0 + k) * H + n0 + tx * 4;
        #pragma unroll
        for (int e = 0; e < 4; ++e)
            Ts[k][tx * 4 + e] = f2bbits(ldf(W, base + e, f));
    }
    __syncthreads();
    #pragma unroll
    for (int it = 0; it < 4; ++it) {
        int n = ty + it * 16;
        ushort4 o;
        o.x = Ts[tx * 4 + 0][n];
        o.y = Ts[tx * 4 + 1][n];
        o.z = Ts[tx * 4 + 2][n];
        o.w = Ts[tx * 4 + 3][n];
        *(ushort4*)&T[(size_t)(n0 + n) * H + k0 + tx * 4] = o;
    }
}

// transpose Vb[S][H] bf16 -> VT[H][S] bf16
__global__ __launch_bounds__(256) void vtrans(
    const bf16* __restrict__ Vb, bf16* __restrict__ VT)
{
    __shared__ unsigned short Ts[64][68];
    const int t = threadIdx.x;
    const int tx = t & 15, ty = t >> 4;
    const int s0 = blockIdx.x * 64;
    const int h0 = blockIdx.y * 64;
    #pragma unroll
    for (int it = 0; it < 4; ++it) {
        int s = ty + it * 16;
        *(ushort4*)&Ts[s][tx * 4] =
            *(const ushort4*)&Vb[(size_t)(s0 + s) * H + h0 + tx * 4];
    }
    __syncthreads();
    #pragma unroll
    for (int it = 0; it < 4; ++it) {
        int hh = ty + it * 16;
        ushort4 o;
        o.x = Ts[tx * 4 + 0][hh];
        o.y = Ts[tx * 4 + 1][hh];
        o.z = Ts[tx * 4 + 2][hh];
        o.w = Ts[tx * 4 + 3][hh];
        *(ushort4*)&VT[(size_t)(h0 + hh) * S + s0 + tx * 4] = o;
    }
}

// ---------------- m97-style 128x128 MFMA GEMM core -------------------------
__device__ __forceinline__ void gemm128_bt(
    const bf16* __restrict__ A, const bf16* __restrict__ BT,
    f32x4 (&acc)[4][4])
{
    const int tid = threadIdx.x;
    const int w = tid >> 6, lane = tid & 63;
    const int l15 = lane & 15, quad = lane >> 4;
    const int wm = (w & 1) * 64, wn = (w >> 1) * 64;
    const int rowb = blockIdx.y * 128;
    const int colb = blockIdx.x * 128;

    __shared__ bf16 As[128 * BK];   // [m][k], rows of 32 bf16 (64 B)
    __shared__ bf16 Bs[128 * BK];   // [n][k]

    for (int kb = 0; kb < H; kb += BK) {
        #pragma unroll
        for (int j = 0; j < 2; ++j) {
            int i = j * 256 + w * 64 + lane;
            gl_lds16(&A[(size_t)(rowb + (i >> 2)) * H + kb + (i & 3) * 8],
                     &As[(size_t)(j * 256 + w * 64) * 8]);
            gl_lds16(&BT[(size_t)(colb + (i >> 2)) * H + kb + (i & 3) * 8],
                     &Bs[(size_t)(j * 256 + w * 64) * 8]);
        }
        __syncthreads();

        bf16x8 af[4], bfr[4];
        #pragma unroll
        for (int mt = 0; mt < 4; ++mt)
            af[mt] = *(const bf16x8*)&As[(wm + mt * 16 + l15) * BK + quad * 8];
        #pragma unroll
        for (int nt = 0; nt < 4; ++nt)
            bfr[nt] = *(const bf16x8*)&Bs[(wn + nt * 16 + l15) * BK + quad * 8];
        #pragma unroll
        for (int mt = 0; mt < 4; ++mt)
            #pragma unroll
            for (int nt = 0; nt < 4; ++nt)
                acc[mt][nt] = __builtin_amdgcn_mfma_f32_16x16x32_bf16(
                    af[mt], bfr[nt], acc[mt][nt], 0, 0, 0);
        __syncthreads();
    }
}

// ---------------- QKV MFMA GEMM -------------------------------------------
__global__ __launch_bounds__(256) void qkv_mfma(
    const bf16* __restrict__ xb,
    const bf16* __restrict__ WTq, const bf16* __restrict__ WTk,
    const bf16* __restrict__ WTv,
    const void* __restrict__ bq, const void* __restrict__ bk,
    const void* __restrict__ bv,
    bf16* __restrict__ Qb, bf16* __restrict__ Kb, bf16* __restrict__ Vb,
    const int* __restrict__ flag)
{
    const bf16* BT; const void* bias; bf16* out;
    if (blockIdx.z == 0)      { BT = WTq; bias = bq; out = Qb; }
    else if (blockIdx.z == 1) { BT = WTk; bias = bk; out = Kb; }
    else                      { BT = WTv; bias = bv; out = Vb; }
    const int f = *flag;

    f32x4 acc[4][4];
    #pragma unroll
    for (int a = 0; a < 4; ++a)
        #pragma unroll
        for (int b = 0; b < 4; ++b) acc[a][b] = (f32x4)0.f;

    gemm128_bt(xb, BT, acc);

    const int tid = threadIdx.x;
    const int w = tid >> 6, lane = tid & 63;
    const int l15 = lane & 15, quad = lane >> 4;
    const int wm = (w & 1) * 64, wn = (w >> 1) * 64;
    const int rowb = blockIdx.y * 128;
    const int colb = blockIdx.x * 128;

    float bvv[4];
    #pragma unroll
    for (int nt = 0; nt < 4; ++nt)
        bvv[nt] = ldf(bias, colb + wn + nt * 16 + l15, f);

    #pragma unroll
    for (int mt = 0; mt < 4; ++mt)
        #pragma unroll
        for (int nt = 0; nt < 4; ++nt)
            #pragma unroll
            for (int r = 0; r < 4; ++r) {
                int m = rowb + wm + mt * 16 + quad * 4 + r;
                int n = colb + wn + nt * 16 + l15;
                out[(size_t)m * H + n] = __float2bfloat16(acc[mt][nt][r] + bvv[nt]);
            }
}

// ---------------- output MFMA GEMM ----------------------------------------
__global__ __launch_bounds__(256) void out_mfma(
    const bf16* __restrict__ Cb, const bf16* __restrict__ WoT,
    const void* __restrict__ bias, void* __restrict__ out,
    const int* __restrict__ flag)
{
    const int f = *flag;
    f32x4 acc[4][4];
    #pragma unroll
    for (int a = 0; a < 4; ++a)
        #pragma unroll
        for (int b = 0; b < 4; ++b) acc[a][b] = (f32x4)0.f;

    gemm128_bt(Cb, WoT, acc);

    const int tid = threadIdx.x;
    const int w = tid >> 6, lane = tid & 63;
    const int l15 = lane & 15, quad = lane >> 4;
    const int wm = (w & 1) * 64, wn = (w >> 1) * 64;
    const int rowb = blockIdx.y * 128;
    const int colb = blockIdx.x * 128;

    float bvv[4];
    #pragma unroll
    for (int nt = 0; nt < 4; ++nt)
        bvv[nt] = ldf(bias, colb + wn + nt * 16 + l15, f);

    #pragma unroll
    for (int mt = 0; mt < 4; ++mt)
        #pragma unroll
        for (int nt = 0; nt < 4; ++nt)
            #pragma unroll
            for (int r = 0; r < 4; ++r) {
                int m = rowb + wm + mt * 16 + quad * 4 + r;
                int n = colb + wn + nt * 16 + l15;
                float v = acc[mt][nt][r] + bvv[nt];
                if (f) ((float*)out)[(size_t)m * H + n] = v;
                else   ((bf16*)out)[(size_t)m * H + n] = __float2bfloat16(v);
            }
}

// ---------------- MFMA flash attention (rel fused in) ----------------------
// block = (64 queries) x (1 head), 4 waves; wave w owns q rows w*16..w*16+15.
__global__ __launch_bounds__(256) void attn_mfma(
    const bf16* __restrict__ Qb, const bf16* __restrict__ Kb,
    const bf16* __restrict__ VT,
    const void* __restrict__ rel_emb, const void* __restrict__ rel_bias,
    const int* __restrict__ att_mask, const int* __restrict__ rel_ids,
    bf16* __restrict__ Cb, const int* __restrict__ flag)
{
    const int h = blockIdx.y;
    const int q0 = blockIdx.x * 64;
    const int tid = threadIdx.x;
    const int w = tid >> 6;
    const int lane = tid & 63;
    const int l15 = lane & 15;
    const int quad = lane >> 4;
    const int f = *flag;

    __shared__ short Qs[64][72];
    __shared__ short Ks[64][72];
    __shared__ short Vs[64][72];
    __shared__ short Ps[64][72];
    __shared__ float Bias[64][64];
    __shared__ float Rl[64][33];
    __shared__ short Es[32][72];     // rel_emb[r][d] bf16, this head
    __shared__ float Rbias[32];

    // ---- stage Q tile ----
    for (int slot = tid; slot < 512; slot += 256) {
        int q = slot >> 3, c = slot & 7;
        *(uint4*)&Qs[q][c * 8] = *(const uint4*)&Qb[(q0 + q) * H + h * DH + c * 8];
    }
    // ---- stage rel_emb (32 rows x 64) + rel_bias ----
    {
        int r = tid >> 3, c8 = (tid & 7) * 8;            // 256 chunks exactly
        if (f) {
            const float* src = (const float*)rel_emb + (r * NH + h) * DH + c8;
            ushort4 o0, o1;
            o0.x = f2bbits(src[0]); o0.y = f2bbits(src[1]);
            o0.z = f2bbits(src[2]); o0.w = f2bbits(src[3]);
            o1.x = f2bbits(src[4]); o1.y = f2bbits(src[5]);
            o1.z = f2bbits(src[6]); o1.w = f2bbits(src[7]);
            *(ushort4*)&Es[r][c8] = o0;
            *(ushort4*)&Es[r][c8 + 4] = o1;
        } else {
            *(uint4*)&Es[r][c8] =
                *(const uint4*)((const bf16*)rel_emb + (r * NH + h) * DH + c8);
        }
        if (tid < RV) Rbias[tid] = ldf(rel_bias, tid * NH + h, f);
    }
    __syncthreads();

    // ---- Q fragments (reused in every k-tile) ----
    bf16x8 aq0 = *(const bf16x8*)&Qs[w * 16 + l15][quad * 8];
    bf16x8 aq1 = *(const bf16x8*)&Qs[w * 16 + l15][32 + quad * 8];

    // ---- Rl[q][r] = Q . rel_emb^T + rel_bias via MFMA (wave-private rows) --
    #pragma unroll
    for (int nt = 0; nt < 2; ++nt) {
        bf16x8 be0 = *(const bf16x8*)&Es[nt * 16 + l15][quad * 8];
        bf16x8 be1 = *(const bf16x8*)&Es[nt * 16 + l15][32 + quad * 8];
        f32x4 c = (f32x4)0.f;
        c = __builtin_amdgcn_mfma_f32_16x16x32_bf16(aq0, be0, c, 0, 0, 0);
        c = __builtin_amdgcn_mfma_f32_16x16x32_bf16(aq1, be1, c, 0, 0, 0);
        float rb = Rbias[nt * 16 + l15];
        #pragma unroll
        for (int r = 0; r < 4; ++r)
            Rl[w * 16 + quad * 4 + r][nt * 16 + l15] = c[r] + rb;
    }
    __syncthreads();   // Bias staging reads all Rl rows

    f32x4 O[4];
    float mrow[4], lrow[4];
    #pragma unroll
    for (int i = 0; i < 4; ++i) { O[i] = (f32x4)0.f; mrow[i] = -1e30f; lrow[i] = 0.f; }

    for (int kt = 0; kt < S; kt += 64) {
        for (int slot = tid; slot < 512; slot += 256) {
            int r = slot >> 3, c = slot & 7;
            *(uint4*)&Ks[r][c * 8] = *(const uint4*)&Kb[(kt + r) * H + h * DH + c * 8];
            *(uint4*)&Vs[r][c * 8] = *(const uint4*)&VT[(size_t)(h * DH + r) * S + kt + c * 8];
        }
        {
            int q = tid >> 2, kg = (tid & 3) * 16;
            const int4* ridp = (const int4*)(rel_ids + (q0 + q) * S + kt + kg);
            const int4* mskp = (const int4*)(att_mask + (q0 + q) * S + kt + kg);
            #pragma unroll
            for (int v4 = 0; v4 < 4; ++v4) {
                int4 rid = ridp[v4];
                int4 msk = mskp[v4];
                Bias[q][kg + v4 * 4 + 0] = Rl[q][rid.x] * 0.125f - 10000.0f * (1.0f - (float)msk.x);
                Bias[q][kg + v4 * 4 + 1] = Rl[q][rid.y] * 0.125f - 10000.0f * (1.0f - (float)msk.y);
                Bias[q][kg + v4 * 4 + 2] = Rl[q][rid.z] * 0.125f - 10000.0f * (1.0f - (float)msk.z);
                Bias[q][kg + v4 * 4 + 3] = Rl[q][rid.w] * 0.125f - 10000.0f * (1.0f - (float)msk.w);
            }
        }
        __syncthreads();

        f32x4 sc[4];
        #pragma unroll
        for (int nt = 0; nt < 4; ++nt) {
            bf16x8 bk0 = *(const bf16x8*)&Ks[nt * 16 + l15][quad * 8];
            bf16x8 bk1 = *(const bf16x8*)&Ks[nt * 16 + l15][32 + quad * 8];
            f32x4 c = (f32x4)0.f;
            c = __builtin_amdgcn_mfma_f32_16x16x32_bf16(aq0, bk0, c, 0, 0, 0);
            c = __builtin_amdgcn_mfma_f32_16x16x32_bf16(aq1, bk1, c, 0, 0, 0);
            sc[nt] = c;
        }
        #pragma unroll
        for (int nt = 0; nt < 4; ++nt)
            #pragma unroll
            for (int r = 0; r < 4; ++r)
                sc[nt][r] = sc[nt][r] * 0.125f + Bias[w * 16 + quad * 4 + r][nt * 16 + l15];

        float alpha[4];
        #pragma unroll
        for (int r = 0; r < 4; ++r) {
            float v = fmaxf(fmaxf(sc[0][r], sc[1][r]), fmaxf(sc[2][r], sc[3][r]));
            v = fmaxf(v, __shfl_xor(v, 1, 64));
            v = fmaxf(v, __shfl_xor(v, 2, 64));
            v = fmaxf(v, __shfl_xor(v, 4, 64));
            v = fmaxf(v, __shfl_xor(v, 8, 64));
            float mnew = fmaxf(mrow[r], v);
            alpha[r] = __expf(mrow[r] - mnew);
            mrow[r] = mnew;
        }
        float rsum[4] = {0.f, 0.f, 0.f, 0.f};
        #pragma unroll
        for (int nt = 0; nt < 4; ++nt)
            #pragma unroll
            for (int r = 0; r < 4; ++r) {
                float p = __expf(sc[nt][r] - mrow[r]);
                sc[nt][r] = p;
                rsum[r] += p;
            }
        #pragma unroll
        for (int r = 0; r < 4; ++r) {
            float v = rsum[r];
            v += __shfl_xor(v, 1, 64);
            v += __shfl_xor(v, 2, 64);
            v += __shfl_xor(v, 4, 64);
            v += __shfl_xor(v, 8, 64);
            lrow[r] = lrow[r] * alpha[r] + v;
            #pragma unroll
            for (int dt = 0; dt < 4; ++dt) O[dt][r] *= alpha[r];
        }

        #pragma unroll
        for (int nt = 0; nt < 4; ++nt)
            #pragma unroll
            for (int r = 0; r < 4; ++r)
                ((unsigned short*)&Ps[w * 16 + quad * 4 + r][nt * 16 + l15])[0] = f2bbits(sc[nt][r]);

        bf16x8 ap0 = *(const bf16x8*)&Ps[w * 16 + l15][quad * 8];
        bf16x8 ap1 = *(const bf16x8*)&Ps[w * 16 + l15][32 + quad * 8];
        #pragma unroll
        for (int dt = 0; dt < 4; ++dt) {
            bf16x8 bv0 = *(const bf16x8*)&Vs[dt * 16 + l15][quad * 8];
            bf16x8 bv1 = *(const bf16x8*)&Vs[dt * 16 + l15][32 + quad * 8];
            O[dt] = __builtin_amdgcn_mfma_f32_16x16x32_bf16(ap0, bv0, O[dt], 0, 0, 0);
            O[dt] = __builtin_amdgcn_mfma_f32_16x16x32_bf16(ap1, bv1, O[dt], 0, 0, 0);
        }
        __syncthreads();
    }

    #pragma unroll
    for (int r = 0; r < 4; ++r) {
        int q = q0 + w * 16 + quad * 4 + r;
        float inv = 1.0f / lrow[r];
        #pragma unroll
        for (int dt = 0; dt < 4; ++dt)
            Cb[(size_t)q * H + h * DH + dt * 16 + l15] = __float2bfloat16(O[dt][r] * inv);
    }
}

extern "C" void kernel_launch(void* const* d_in, const int* in_sizes, int n_in,
                              void* d_out, int out_size, void* d_ws, size_t ws_size,
                              hipStream_t stream)
{
    const void* x        = d_in[0];
    const int*  att_mask = (const int*)d_in[1];
    const int*  rel_ids  = (const int*)d_in[2];
    const void* Wq = d_in[3];
    const void* bq = d_in[4];
    const void* Wk = d_in[5];
    const void* bk = d_in[6];
    const void* Wv = d_in[7];
    const void* bv = d_in[8];
    const void* rel_emb  = d_in[9];
    const void* rel_bias = d_in[10];
    const void* Wo = d_in[11];
    const void* bo = d_in[12];

    char* p = (char*)d_ws;
    bf16* xb  = (bf16*)p; p += (size_t)S * H * 2;
    bf16* WTq = (bf16*)p; p += (size_t)H * H * 2;
    bf16* WTk = (bf16*)p; p += (size_t)H * H * 2;
    bf16* WTv = (bf16*)p; p += (size_t)H * H * 2;
    bf16* WoT = (bf16*)p; p += (size_t)H * H * 2;
    bf16* Qb  = (bf16*)p; p += (size_t)S * H * 2;
    bf16* Kb  = (bf16*)p; p += (size_t)S * H * 2;
    bf16* Vb  = (bf16*)p; p += (size_t)S * H * 2;
    bf16* VT  = (bf16*)p; p += (size_t)S * H * 2;
    bf16* Cb  = (bf16*)p; p += (size_t)S * H * 2;
    int* flag = (int*)p;

    detect_dtype<<<1, 256, 0, stream>>>((const unsigned int*)x, flag);

    convert_x<<<(S * H) / 1024, 256, 0, stream>>>(x, xb, flag);
    wtrans<<<dim3(H / 64, H / 64, 4), 256, 0, stream>>>(
        Wq, Wk, Wv, Wo, WTq, WTk, WTv, WoT, flag);

    qkv_mfma<<<dim3(H / 128, S / 128, 3), 256, 0, stream>>>(
        xb, WTq, WTk, WTv, bq, bk, bv, Qb, Kb, Vb, flag);

    vtrans<<<dim3(S / 64, H / 64), 256, 0, stream>>>(Vb, VT);

    attn_mfma<<<dim3(S / 64, NH), 256, 0, stream>>>(
        Qb, Kb, VT, rel_emb, rel_bias, att_mask, rel_ids, Cb, flag);

    out_mfma<<<dim3(H / 128, S / 128), 256, 0, stream>>>(Cb, WoT, bo, d_out, flag);
}